// Round 8
// baseline (346.945 us; speedup 1.0000x reference)
//
#include <hip/hip_runtime.h>

typedef unsigned short u16;
typedef unsigned int   u32;
typedef short bf16x8 __attribute__((ext_vector_type(8)));
typedef float f32x4  __attribute__((ext_vector_type(4)));

__device__ __forceinline__ float bf_lo(u32 u){ return __uint_as_float(u << 16); }
__device__ __forceinline__ float bf_hi(u32 u){ return __uint_as_float(u & 0xffff0000u); }
__device__ __forceinline__ u16 bf16r(float f){
  u32 u = __float_as_uint(f);
  u += 0x7fffu + ((u >> 16) & 1u);
  return (u16)(u >> 16);
}
__device__ __forceinline__ u32 pack2(float a, float b){
  return (u32)bf16r(a) | ((u32)bf16r(b) << 16);
}
// truncating bf16 pair-pack (relative err 2^-8, fine for P)
__device__ __forceinline__ u32 pk_trunc(float a, float b){
  return (__float_as_uint(a) >> 16) | (__float_as_uint(b) & 0xffff0000u);
}
__device__ __forceinline__ float gelu_f(float x){
  float t = 0.7978845608028654f * (x + 0.044715f * x * x * x);
  t = fminf(fmaxf(t, -12.f), 12.f);
  float e = __expf(2.f * t);
  float th = (e - 1.f) / (e + 1.f);
  return 0.5f * x * (1.f + th);
}
// async global->LDS, 16B/lane; LDS dest = wave-uniform base + lane*16 (m104)
__device__ __forceinline__ void glds16(const void* g, void* l) {
  __builtin_amdgcn_global_load_lds(
      (const __attribute__((address_space(1))) void*)g,
      (__attribute__((address_space(3))) void*)l, 16, 0, 0);
}

#define QSCALE 0.1803368801111204f   /* 0.125 * log2(e): scores land in exp2 domain */

// ---------------- weight transpose+convert: W fp32 [K,N] -> Wt bf16 [N,K] ----
__global__ __launch_bounds__(256) void wt_k(const float* __restrict__ W,
                                            u16* __restrict__ Wt, int K, int N) {
  __shared__ float t[32][33];
  int k0 = blockIdx.x * 32, n0 = blockIdx.y * 32;
  int tx = threadIdx.x & 31, ty = threadIdx.x >> 5;
  #pragma unroll
  for (int i = 0; i < 32; i += 8)
    t[ty + i][tx] = W[(size_t)(k0 + ty + i) * N + n0 + tx];
  __syncthreads();
  #pragma unroll
  for (int i = 0; i < 32; i += 8)
    Wt[(size_t)(n0 + ty + i) * K + k0 + tx] = bf16r(t[tx][ty + i]);
}

// ---------------- V transpose: qkv bf16 [4096,3072] (v part) -> Vt [32,64,2048]
__global__ __launch_bounds__(256) void vt_k(const u16* __restrict__ qkv,
                                            u16* __restrict__ Vt) {
  __shared__ u16 tl[32][33];
  int t0 = blockIdx.x * 32;
  int bh = blockIdx.y >> 1, d0 = (blockIdx.y & 1) * 32;
  int bb = bh >> 4, h = bh & 15;
  int tx = threadIdx.x & 31, ty = threadIdx.x >> 5;
  #pragma unroll
  for (int i = 0; i < 32; i += 8)
    tl[ty + i][tx] = qkv[(size_t)(bb*2048 + t0 + ty + i)*3072 + 2048 + h*64 + d0 + tx];
  __syncthreads();
  #pragma unroll
  for (int i = 0; i < 32; i += 8)
    Vt[((size_t)bh*64 + d0 + ty + i)*2048 + t0 + tx] = tl[tx][ty + i];
}

// ---------------- layernorm: fp32 [rows,1024] -> bf16 ----------------------
__global__ __launch_bounds__(256) void ln_k(const float* __restrict__ x,
                                            const float* __restrict__ g,
                                            const float* __restrict__ bta,
                                            u16* __restrict__ out) {
  int row = blockIdx.x, tid = threadIdx.x;
  const float4 xv = ((const float4*)(x + (size_t)row * 1024))[tid];
  float s = xv.x + xv.y + xv.z + xv.w;
  float q = xv.x*xv.x + xv.y*xv.y + xv.z*xv.z + xv.w*xv.w;
  #pragma unroll
  for (int off = 32; off > 0; off >>= 1) {
    s += __shfl_down(s, off);
    q += __shfl_down(q, off);
  }
  __shared__ float ss[4], sq[4];
  if ((tid & 63) == 0) { ss[tid >> 6] = s; sq[tid >> 6] = q; }
  __syncthreads();
  s = ss[0] + ss[1] + ss[2] + ss[3];
  q = sq[0] + sq[1] + sq[2] + sq[3];
  float mu = s * (1.f/1024.f);
  float rs = rsqrtf(q * (1.f/1024.f) - mu*mu + 1e-5f);
  const float4 gv = ((const float4*)g)[tid];
  const float4 bv = ((const float4*)bta)[tid];
  uint2 o;
  o.x = pack2((xv.x-mu)*rs*gv.x + bv.x, (xv.y-mu)*rs*gv.y + bv.y);
  o.y = pack2((xv.z-mu)*rs*gv.z + bv.z, (xv.w-mu)*rs*gv.w + bv.w);
  ((uint2*)(out + (size_t)row * 1024))[tid] = o;
}

// ---------------- GEMM: C = A[M,K(lda)]bf16 @ Bt[N,K(lda)]^T + epilogue -----
// Single-buffered 2-barrier K-loop, MI=2 (TM=64): 24.6KB LDS, VGPR~48 ->
// ~6 blocks/CU residency; cross-block overlap beats bigger tiles (R5 vs R6/R7).
// MODE 0: bf16 = v+b   1/3: f32 = v+b+resid   2: bf16 = gelu(v+b)
// MODE 4: bf16 = (v+b) * (col<1024 ? QSCALE : 1)   [qkv: pre-scale q for attn]
// MODE 5: split-K partial, bf16 = v; blockIdx.y = sp*8 + ncol; A/Bt col-offset
//         sp*K, out + sp*M*N.
template<int MODE, int MI, int LB>
__global__ __launch_bounds__(256, LB) void gemm_k(
    const u16* __restrict__ A, const u16* __restrict__ Bt,
    const float* __restrict__ bias, const float* __restrict__ resid,
    void* __restrict__ out, int M, int N, int K, int lda)
{
  constexpr int TM = MI * 32;
  __shared__ u16 Al[TM * 64];
  __shared__ u16 Bl[128 * 64];
  const int tid = threadIdx.x;
  const int by = blockIdx.y;
  const int sp = (MODE == 5) ? (by >> 3) : 0;
  const int n0 = (MODE == 5) ? ((by & 7) * 128) : (by * 128);
  const size_t koff = (size_t)sp * K;
  const int m0 = blockIdx.x * TM;
  const int wave = tid >> 6, lane = tid & 63;
  const int wm = (wave >> 1) * (MI * 16), wn = (wave & 1) * 64;
  const int l15 = lane & 15, quad = lane >> 4;
  const int sr = lane >> 3, cs = lane & 7;
  f32x4 acc[MI][4];
  const f32x4 zero = {0.f, 0.f, 0.f, 0.f};
  #pragma unroll
  for (int i = 0; i < MI; ++i)
    #pragma unroll
    for (int j = 0; j < 4; ++j)
      acc[i][j] = zero;
  for (int k0 = 0; k0 < K; k0 += 64) {
    __syncthreads();
    #pragma unroll
    for (int it = 0; it < MI; ++it) {
      int r = it*32 + wave*8 + sr;
      int c = cs ^ (r & 7);
      glds16(&A[(size_t)(m0 + r) * lda + koff + k0 + c*8], &Al[(it*32 + wave*8) * 64]);
    }
    #pragma unroll
    for (int it = 0; it < 4; ++it) {
      int r = it*32 + wave*8 + sr;
      int c = cs ^ (r & 7);
      glds16(&Bt[(size_t)(n0 + r) * lda + koff + k0 + c*8], &Bl[(it*32 + wave*8) * 64]);
    }
    __syncthreads();
    #pragma unroll
    for (int kk = 0; kk < 2; ++kk) {
      bf16x8 af[MI], bfr[4];
      #pragma unroll
      for (int i = 0; i < MI; ++i) {
        int R = wm + i*16 + l15;
        af[i] = *(const bf16x8*)&Al[R*64 + ((kk*4 + quad) ^ (R & 7)) * 8];
      }
      #pragma unroll
      for (int j = 0; j < 4; ++j) {
        int R = wn + j*16 + l15;
        bfr[j] = *(const bf16x8*)&Bl[R*64 + ((kk*4 + quad) ^ (R & 7)) * 8];
      }
      #pragma unroll
      for (int i = 0; i < MI; ++i)
        #pragma unroll
        for (int j = 0; j < 4; ++j)
          acc[i][j] = __builtin_amdgcn_mfma_f32_16x16x32_bf16(af[i], bfr[j], acc[i][j], 0, 0, 0);
    }
  }
  #pragma unroll
  for (int i = 0; i < MI; ++i) {
    #pragma unroll
    for (int j = 0; j < 4; ++j) {
      int col = n0 + wn + j*16 + l15;
      float bv = (MODE == 5) ? 0.f : bias[col];
      float sc = (MODE == 4 && col < 1024) ? QSCALE : 1.0f;
      #pragma unroll
      for (int r = 0; r < 4; ++r) {
        int row = m0 + wm + i*16 + quad*4 + r;
        size_t idx = (size_t)row * N + col;
        float v = acc[i][j][r] + bv;
        if constexpr (MODE == 0)      ((u16*)out)[idx] = bf16r(v);
        else if constexpr (MODE == 1) ((float*)out)[idx] = v + resid[idx];
        else if constexpr (MODE == 2) ((u16*)out)[idx] = bf16r(gelu_f(v));
        else if constexpr (MODE == 4) ((u16*)out)[idx] = bf16r(v * sc);
        else if constexpr (MODE == 5) ((u16*)out)[(size_t)sp*M*N + idx] = bf16r(v);
        else                          ((float*)out)[idx] = v + resid[idx];
      }
    }
  }
}

// ---------------- split-K combine: out = p0 + p1 + bias + x2 (fp32) ---------
__global__ __launch_bounds__(256) void cmb_k(const u16* __restrict__ p,
                                             const float* __restrict__ bias,
                                             const float* __restrict__ x2,
                                             float* __restrict__ out) {
  int row = blockIdx.x, t = threadIdx.x;
  size_t i = (size_t)row * 1024 + t*4;
  uint2 a = *(const uint2*)&p[i];
  uint2 b = *(const uint2*)&p[4194304 + i];
  float4 xv = ((const float4*)x2)[i >> 2];
  float4 bv = ((const float4*)bias)[t];
  float4 o;
  o.x = bf_lo(a.x) + bf_lo(b.x) + bv.x + xv.x;
  o.y = bf_hi(a.x) + bf_hi(b.x) + bv.y + xv.y;
  o.z = bf_lo(a.y) + bf_lo(b.y) + bv.z + xv.z;
  o.w = bf_hi(a.y) + bf_hi(b.y) + bv.w + xv.w;
  ((float4*)out)[i >> 2] = o;
}

// ---------------- MFMA flash attention, S^T, 64-q blocks, fixed-max ---------
// Grid 1024 = 4 blocks/CU (16 waves/CU): cross-block overlap fills the serial
// QK->exp->pack->PV chain (R7: 2 blocks/CU gave 3x stall factor). Single-
// buffered K/V (25.6KB LDS); heavy q-tiles dispatched first.
__global__ __launch_bounds__(256, 4) void attn_k(const u16* __restrict__ qkv,
                                                 const u16* __restrict__ Vt,
                                                 u16* __restrict__ y) {
  __shared__ u16 Kl[64*64];      // keys x d, XOR-swizzled chunks
  __shared__ u16 Vl[64*64];      // d x keys, XOR-swizzled chunks
  __shared__ u16 Pw[4*16*72];    // per-wave P: 16 q x 64 keys bf16 (+8 pad)
  const int tid = threadIdx.x;
  const int bh = blockIdx.x & 31, bb = bh >> 4, h = bh & 15;
  const int qt = 31 - (int)(blockIdx.x >> 5);   // heavy first
  const int w = tid >> 6, lane = tid & 63;
  const int l15 = lane & 15, quad = lane >> 4;
  const int sr = lane >> 3, cs = lane & 7;
  u16* Pme = Pw + w * (16*72);
  const int w16l = w*16 + l15;
  const int dquad = quad*4;

  const u16* qp = qkv + ((size_t)(bb*2048 + qt*64 + w16l))*3072 + h*64 + quad*8;
  const bf16x8 aq0 = *(const bf16x8*)qp;
  const bf16x8 aq1 = *(const bf16x8*)(qp + 32);

  f32x4 o[4];
  const f32x4 zero = {0.f,0.f,0.f,0.f};
  #pragma unroll
  for (int dt = 0; dt < 4; ++dt) o[dt] = zero;
  float l = 0.f;

  const u16* kbase = qkv + (size_t)bb*2048*3072 + 1024 + h*64;
  const u16* vbase = Vt + (size_t)bh*64*2048;

  for (int kt = 0; kt <= qt; ++kt) {
    __syncthreads();
    #pragma unroll
    for (int it = 0; it < 2; ++it) {
      int r = it*32 + w*8 + sr;
      int c = cs ^ (r & 7);
      glds16(kbase + (size_t)(kt*64 + r)*3072 + c*8, &Kl[(it*32 + w*8) * 64]);
      glds16(vbase + (size_t)r*2048 + kt*64 + c*8,   &Vl[(it*32 + w*8) * 64]);
    }
    __syncthreads();
    bf16x8 ak[4][2], av[4][2];
    #pragma unroll
    for (int nt = 0; nt < 4; ++nt) {
      int R = nt*16 + l15;
      #pragma unroll
      for (int kk = 0; kk < 2; ++kk) {
        ak[nt][kk] = *(const bf16x8*)&Kl[R*64 + ((kk*4 + quad) ^ (R & 7)) * 8];
        av[nt][kk] = *(const bf16x8*)&Vl[R*64 + ((kk*4 + quad) ^ (R & 7)) * 8];
      }
    }
    f32x4 sv[4];
    #pragma unroll
    for (int nt = 0; nt < 4; ++nt) {
      f32x4 s = zero;
      s = __builtin_amdgcn_mfma_f32_16x16x32_bf16(ak[nt][0], aq0, s, 0, 0, 0);
      s = __builtin_amdgcn_mfma_f32_16x16x32_bf16(ak[nt][1], aq1, s, 0, 0, 0);
      sv[nt] = s;
    }
    if (kt == qt) {                           // diagonal tile: causal mask
      #pragma unroll
      for (int nt = 0; nt < 4; ++nt)
        #pragma unroll
        for (int r = 0; r < 4; ++r)
          if (nt*16 + dquad + r > w16l) sv[nt][r] = -1e30f;
    }
    float pv[4][4];
    #pragma unroll
    for (int nt = 0; nt < 4; ++nt)
      #pragma unroll
      for (int r = 0; r < 4; ++r)
        pv[nt][r] = exp2f(sv[nt][r]);         // fixed max=0 (bounded scores)
    l += ((pv[0][0]+pv[0][1])+(pv[0][2]+pv[0][3]))
       + ((pv[1][0]+pv[1][1])+(pv[1][2]+pv[1][3]))
       + ((pv[2][0]+pv[2][1])+(pv[2][2]+pv[2][3]))
       + ((pv[3][0]+pv[3][1])+(pv[3][2]+pv[3][3]));
    #pragma unroll
    for (int nt = 0; nt < 4; ++nt) {
      uint2 pr;
      pr.x = pk_trunc(pv[nt][0], pv[nt][1]);
      pr.y = pk_trunc(pv[nt][2], pv[nt][3]);
      *(uint2*)&Pme[l15*72 + nt*16 + dquad] = pr;
    }
    const bf16x8 bp0 = *(const bf16x8*)&Pme[l15*72 + quad*8];
    const bf16x8 bp1 = *(const bf16x8*)&Pme[l15*72 + 32 + quad*8];
    #pragma unroll
    for (int dt = 0; dt < 4; ++dt) {
      o[dt] = __builtin_amdgcn_mfma_f32_16x16x32_bf16(av[dt][0], bp0, o[dt], 0, 0, 0);
      o[dt] = __builtin_amdgcn_mfma_f32_16x16x32_bf16(av[dt][1], bp1, o[dt], 0, 0, 0);
    }
  }
  float lt = l;
  lt += __shfl_xor(lt, 16);
  lt += __shfl_xor(lt, 32);
  float inv = 1.f / lt;
  u16* yp = y + ((size_t)(bb*2048 + qt*64 + w16l))*1024 + h*64;
  #pragma unroll
  for (int dt = 0; dt < 4; ++dt) {
    uint2 pk;
    pk.x = pack2(o[dt][0]*inv, o[dt][1]*inv);
    pk.y = pack2(o[dt][2]*inv, o[dt][3]*inv);
    *(uint2*)(yp + dt*16 + dquad) = pk;
  }
}

// ---------------------------------------------------------------------------
extern "C" void kernel_launch(void* const* d_in, const int* in_sizes, int n_in,
                              void* d_out, int out_size, void* d_ws, size_t ws_size,
                              hipStream_t stream) {
  const float* x      = (const float*)d_in[0];
  const float* ln1_g  = (const float*)d_in[1];
  const float* ln1_b  = (const float*)d_in[2];
  const float* w_attn = (const float*)d_in[3];
  const float* b_attn = (const float*)d_in[4];
  const float* w_proj = (const float*)d_in[5];
  const float* b_proj = (const float*)d_in[6];
  const float* ln2_g  = (const float*)d_in[7];
  const float* ln2_b  = (const float*)d_in[8];
  const float* w_fc   = (const float*)d_in[9];
  const float* b_fc   = (const float*)d_in[10];
  const float* w_fc2  = (const float*)d_in[11];
  const float* b_fc2  = (const float*)d_in[12];

  char* ws = (char*)d_ws;
  u16*   wt_attn = (u16*)(ws);                 // [3072,1024] bf16
  u16*   wt_proj = (u16*)(ws + 6291456);       // [1024,1024]
  u16*   wt_fc   = (u16*)(ws + 8388608);       // [4096,1024]
  u16*   wt_fc2  = (u16*)(ws + 16777216);      // [1024,4096]
  u16*   h1      = (u16*)(ws + 25165824);      // [4096,1024] bf16 (dead after qkv GEMM)
  u16*   qkvb    = (u16*)(ws + 33554432);      // [4096,3072] bf16
  u16*   yb      = (u16*)(ws + 58720256);      // [4096,1024] bf16
  float* x2      = (float*)(ws + 67108864);    // [4096,1024] f32
  u16*   h2  = h1;
  u16*   vtb = h1;                             // Vt [32,64,2048] bf16, aliases h1
  u16*   act = qkvb;                           // [4096,4096] bf16 (yb dead by then)
  u16*   pk2 = (u16*)(ws);                     // fc2 partials [2][4096,1024] bf16
                                               // (aliases wt_* head, dead after fc)

  wt_k<<<dim3(32, 96),  256, 0, stream>>>(w_attn, wt_attn, 1024, 3072);
  wt_k<<<dim3(32, 32),  256, 0, stream>>>(w_proj, wt_proj, 1024, 1024);
  wt_k<<<dim3(32, 128), 256, 0, stream>>>(w_fc,   wt_fc,   1024, 4096);
  wt_k<<<dim3(128, 32), 256, 0, stream>>>(w_fc2,  wt_fc2,  4096, 1024);

  ln_k<<<4096, 256, 0, stream>>>(x, ln1_g, ln1_b, h1);
  gemm_k<4,2,3><<<dim3(64, 24), 256, 0, stream>>>(h1, wt_attn, b_attn, nullptr,
                                                  (void*)qkvb, 4096, 3072, 1024, 1024);
  vt_k<<<dim3(64, 64), 256, 0, stream>>>(qkvb, vtb);      // h1 dead now
  attn_k<<<dim3(1024), 256, 0, stream>>>(qkvb, vtb, yb);
  gemm_k<1,2,3><<<dim3(64, 8), 256, 0, stream>>>(yb, wt_proj, b_proj, x,
                                                 (void*)x2, 4096, 1024, 1024, 1024);
  ln_k<<<4096, 256, 0, stream>>>(x2, ln2_g, ln2_b, h2);   // Vt dead now
  gemm_k<2,2,3><<<dim3(64, 32), 256, 0, stream>>>(h2, wt_fc, b_fc, nullptr,
                                                  (void*)act, 4096, 4096, 1024, 1024);
  // fc2 split-K x2, single dispatch (1024 blocks = 4/CU), bf16 partials
  gemm_k<5,2,3><<<dim3(64, 16), 256, 0, stream>>>(act, wt_fc2, b_fc2, nullptr,
                                                  (void*)pk2, 4096, 1024, 2048, 4096);
  cmb_k<<<4096, 256, 0, stream>>>(pk2, b_fc2, x2, (float*)d_out);
}

// Round 9
// 318.438 us; speedup vs baseline: 1.0895x; 1.0895x over previous
//
#include <hip/hip_runtime.h>

typedef unsigned short u16;
typedef unsigned int   u32;
typedef short bf16x8 __attribute__((ext_vector_type(8)));
typedef float f32x4  __attribute__((ext_vector_type(4)));

__device__ __forceinline__ float bf_lo(u32 u){ return __uint_as_float(u << 16); }
__device__ __forceinline__ float bf_hi(u32 u){ return __uint_as_float(u & 0xffff0000u); }
__device__ __forceinline__ u16 bf16r(float f){
  u32 u = __float_as_uint(f);
  u += 0x7fffu + ((u >> 16) & 1u);
  return (u16)(u >> 16);
}
__device__ __forceinline__ u32 pack2(float a, float b){
  return (u32)bf16r(a) | ((u32)bf16r(b) << 16);
}
// truncating bf16 pair-pack (relative err 2^-8, fine for P)
__device__ __forceinline__ u32 pk_trunc(float a, float b){
  return (__float_as_uint(a) >> 16) | (__float_as_uint(b) & 0xffff0000u);
}
__device__ __forceinline__ float gelu_f(float x){
  float t = 0.7978845608028654f * (x + 0.044715f * x * x * x);
  t = fminf(fmaxf(t, -12.f), 12.f);
  float e = __expf(2.f * t);
  float th = (e - 1.f) / (e + 1.f);
  return 0.5f * x * (1.f + th);
}
// async global->LDS, 16B/lane; LDS dest = wave-uniform base + lane*16 (m104)
__device__ __forceinline__ void glds16(const void* g, void* l) {
  __builtin_amdgcn_global_load_lds(
      (const __attribute__((address_space(1))) void*)g,
      (__attribute__((address_space(3))) void*)l, 16, 0, 0);
}

#define QSCALE 0.1803368801111204f   /* 0.125 * log2(e): scores land in exp2 domain */

// ---------------- prep bodies (merged into one dispatch) --------------------
__device__ __forceinline__ void wt_body(const float* __restrict__ W,
                                        u16* __restrict__ Wt, int K, int N,
                                        int kx, int nx) {
  __shared__ float t[32][33];
  int k0 = kx * 32, n0 = nx * 32;
  int tx = threadIdx.x & 31, ty = threadIdx.x >> 5;
  #pragma unroll
  for (int i = 0; i < 32; i += 8)
    t[ty + i][tx] = W[(size_t)(k0 + ty + i) * N + n0 + tx];
  __syncthreads();
  #pragma unroll
  for (int i = 0; i < 32; i += 8)
    Wt[(size_t)(n0 + ty + i) * K + k0 + tx] = bf16r(t[tx][ty + i]);
}

__device__ __forceinline__ void ln_body(const float* __restrict__ x,
                                        const float* __restrict__ g,
                                        const float* __restrict__ bta,
                                        u16* __restrict__ out, int row) {
  int tid = threadIdx.x;
  const float4 xv = ((const float4*)(x + (size_t)row * 1024))[tid];
  float s = xv.x + xv.y + xv.z + xv.w;
  float q = xv.x*xv.x + xv.y*xv.y + xv.z*xv.z + xv.w*xv.w;
  #pragma unroll
  for (int off = 32; off > 0; off >>= 1) {
    s += __shfl_down(s, off);
    q += __shfl_down(q, off);
  }
  __shared__ float ss[4], sq[4];
  if ((tid & 63) == 0) { ss[tid >> 6] = s; sq[tid >> 6] = q; }
  __syncthreads();
  s = ss[0] + ss[1] + ss[2] + ss[3];
  q = sq[0] + sq[1] + sq[2] + sq[3];
  float mu = s * (1.f/1024.f);
  float rs = rsqrtf(q * (1.f/1024.f) - mu*mu + 1e-5f);
  const float4 gv = ((const float4*)g)[tid];
  const float4 bv = ((const float4*)bta)[tid];
  uint2 o;
  o.x = pack2((xv.x-mu)*rs*gv.x + bv.x, (xv.y-mu)*rs*gv.y + bv.y);
  o.y = pack2((xv.z-mu)*rs*gv.z + bv.z, (xv.w-mu)*rs*gv.w + bv.w);
  ((uint2*)(out + (size_t)row * 1024))[tid] = o;
}

// all 4 weight transposes + LN1 in one flat-grid dispatch (cuts 4 launch gaps)
__global__ __launch_bounds__(256) void prep_k(
    const float* __restrict__ w_attn, const float* __restrict__ w_proj,
    const float* __restrict__ w_fc,   const float* __restrict__ w_fc2,
    u16* __restrict__ wt_attn, u16* __restrict__ wt_proj,
    u16* __restrict__ wt_fc,   u16* __restrict__ wt_fc2,
    const float* __restrict__ x, const float* __restrict__ g,
    const float* __restrict__ b, u16* __restrict__ h1)
{
  int i = blockIdx.x;
  if (i < 3072)       wt_body(w_attn, wt_attn, 1024, 3072, i & 31, i >> 5);
  else if (i < 4096)  { int j = i - 3072; wt_body(w_proj, wt_proj, 1024, 1024, j & 31, j >> 5); }
  else if (i < 8192)  { int j = i - 4096; wt_body(w_fc,   wt_fc,   1024, 4096, j & 31, j >> 5); }
  else if (i < 12288) { int j = i - 8192; wt_body(w_fc2,  wt_fc2,  4096, 1024, j & 127, j >> 7); }
  else                ln_body(x, g, b, h1, i - 12288);
}

// ---------------- V transpose: qkv bf16 [4096,3072] (v part) -> Vt [32,64,2048]
__global__ __launch_bounds__(256) void vt_k(const u16* __restrict__ qkv,
                                            u16* __restrict__ Vt) {
  __shared__ u16 tl[32][33];
  int t0 = blockIdx.x * 32;
  int bh = blockIdx.y >> 1, d0 = (blockIdx.y & 1) * 32;
  int bb = bh >> 4, h = bh & 15;
  int tx = threadIdx.x & 31, ty = threadIdx.x >> 5;
  #pragma unroll
  for (int i = 0; i < 32; i += 8)
    tl[ty + i][tx] = qkv[(size_t)(bb*2048 + t0 + ty + i)*3072 + 2048 + h*64 + d0 + tx];
  __syncthreads();
  #pragma unroll
  for (int i = 0; i < 32; i += 8)
    Vt[((size_t)bh*64 + d0 + ty + i)*2048 + t0 + tx] = tl[tx][ty + i];
}

// ---------------- layernorm (standalone, for LN2) ---------------------------
__global__ __launch_bounds__(256) void ln_k(const float* __restrict__ x,
                                            const float* __restrict__ g,
                                            const float* __restrict__ bta,
                                            u16* __restrict__ out) {
  ln_body(x, g, bta, out, blockIdx.x);
}

// ---------------- GEMM: C = A[M,K(lda)]bf16 @ Bt[N,K(lda)]^T + epilogue -----
// Single-buffered 2-barrier K-loop. MI=4 (TM=128, 32KB LDS) for the big
// GEMMs (R7+m97 evidence: 2x MFMA/iter amortizes staging VALU+latency);
// MI=2 for N=1024 GEMMs (grid parallelism).
// MODE 0: bf16 = v+b   1/3: f32 = v+b+resid   2: bf16 = gelu(v+b)
// MODE 4: bf16 = (v+b) * (col<1024 ? QSCALE : 1)   [qkv: pre-scale q for attn]
// MODE 5: split-K partial, bf16 = v; blockIdx.y = sp*8 + ncol; A/Bt col-offset
//         sp*K, out + sp*M*N.
template<int MODE, int MI, int LB>
__global__ __launch_bounds__(256, LB) void gemm_k(
    const u16* __restrict__ A, const u16* __restrict__ Bt,
    const float* __restrict__ bias, const float* __restrict__ resid,
    void* __restrict__ out, int M, int N, int K, int lda)
{
  constexpr int TM = MI * 32;
  __shared__ u16 Al[TM * 64];
  __shared__ u16 Bl[128 * 64];
  const int tid = threadIdx.x;
  const int by = blockIdx.y;
  const int sp = (MODE == 5) ? (by >> 3) : 0;
  const int n0 = (MODE == 5) ? ((by & 7) * 128) : (by * 128);
  const size_t koff = (size_t)sp * K;
  const int m0 = blockIdx.x * TM;
  const int wave = tid >> 6, lane = tid & 63;
  const int wm = (wave >> 1) * (MI * 16), wn = (wave & 1) * 64;
  const int l15 = lane & 15, quad = lane >> 4;
  const int sr = lane >> 3, cs = lane & 7;
  f32x4 acc[MI][4];
  const f32x4 zero = {0.f, 0.f, 0.f, 0.f};
  #pragma unroll
  for (int i = 0; i < MI; ++i)
    #pragma unroll
    for (int j = 0; j < 4; ++j)
      acc[i][j] = zero;
  for (int k0 = 0; k0 < K; k0 += 64) {
    __syncthreads();
    #pragma unroll
    for (int it = 0; it < MI; ++it) {
      int r = it*32 + wave*8 + sr;
      int c = cs ^ (r & 7);
      glds16(&A[(size_t)(m0 + r) * lda + koff + k0 + c*8], &Al[(it*32 + wave*8) * 64]);
    }
    #pragma unroll
    for (int it = 0; it < 4; ++it) {
      int r = it*32 + wave*8 + sr;
      int c = cs ^ (r & 7);
      glds16(&Bt[(size_t)(n0 + r) * lda + koff + k0 + c*8], &Bl[(it*32 + wave*8) * 64]);
    }
    __syncthreads();
    #pragma unroll
    for (int kk = 0; kk < 2; ++kk) {
      bf16x8 af[MI], bfr[4];
      #pragma unroll
      for (int i = 0; i < MI; ++i) {
        int R = wm + i*16 + l15;
        af[i] = *(const bf16x8*)&Al[R*64 + ((kk*4 + quad) ^ (R & 7)) * 8];
      }
      #pragma unroll
      for (int j = 0; j < 4; ++j) {
        int R = wn + j*16 + l15;
        bfr[j] = *(const bf16x8*)&Bl[R*64 + ((kk*4 + quad) ^ (R & 7)) * 8];
      }
      #pragma unroll
      for (int i = 0; i < MI; ++i)
        #pragma unroll
        for (int j = 0; j < 4; ++j)
          acc[i][j] = __builtin_amdgcn_mfma_f32_16x16x32_bf16(af[i], bfr[j], acc[i][j], 0, 0, 0);
    }
  }
  #pragma unroll
  for (int i = 0; i < MI; ++i) {
    #pragma unroll
    for (int j = 0; j < 4; ++j) {
      int col = n0 + wn + j*16 + l15;
      float bv = (MODE == 5) ? 0.f : bias[col];
      float sc = (MODE == 4 && col < 1024) ? QSCALE : 1.0f;
      #pragma unroll
      for (int r = 0; r < 4; ++r) {
        int row = m0 + wm + i*16 + quad*4 + r;
        size_t idx = (size_t)row * N + col;
        float v = acc[i][j][r] + bv;
        if constexpr (MODE == 0)      ((u16*)out)[idx] = bf16r(v);
        else if constexpr (MODE == 1) ((float*)out)[idx] = v + resid[idx];
        else if constexpr (MODE == 2) ((u16*)out)[idx] = bf16r(gelu_f(v));
        else if constexpr (MODE == 4) ((u16*)out)[idx] = bf16r(v * sc);
        else if constexpr (MODE == 5) ((u16*)out)[(size_t)sp*M*N + idx] = bf16r(v);
        else                          ((float*)out)[idx] = v + resid[idx];
      }
    }
  }
}

// ---------------- split-K combine: out = p0 + p1 + bias + x2 (fp32) ---------
__global__ __launch_bounds__(256) void cmb_k(const u16* __restrict__ p,
                                             const float* __restrict__ bias,
                                             const float* __restrict__ x2,
                                             float* __restrict__ out) {
  int row = blockIdx.x, t = threadIdx.x;
  size_t i = (size_t)row * 1024 + t*4;
  uint2 a = *(const uint2*)&p[i];
  uint2 b = *(const uint2*)&p[4194304 + i];
  float4 xv = ((const float4*)x2)[i >> 2];
  float4 bv = ((const float4*)bias)[t];
  float4 o;
  o.x = bf_lo(a.x) + bf_lo(b.x) + bv.x + xv.x;
  o.y = bf_hi(a.x) + bf_hi(b.x) + bv.y + xv.y;
  o.z = bf_lo(a.y) + bf_lo(b.y) + bv.z + xv.z;
  o.w = bf_hi(a.y) + bf_hi(b.y) + bv.w + xv.w;
  ((float4*)out)[i >> 2] = o;
}

// ---------------- MFMA flash attention, S^T, 64-q blocks, fixed-max ---------
// Grid 1024 = 4 blocks/CU (16 waves/CU): cross-block overlap fills the serial
// QK->exp->pack->PV chain. Single-buffered K/V (25.6KB LDS); heavy tiles first.
__global__ __launch_bounds__(256, 4) void attn_k(const u16* __restrict__ qkv,
                                                 const u16* __restrict__ Vt,
                                                 u16* __restrict__ y) {
  __shared__ u16 Kl[64*64];      // keys x d, XOR-swizzled chunks
  __shared__ u16 Vl[64*64];      // d x keys, XOR-swizzled chunks
  __shared__ u16 Pw[4*16*72];    // per-wave P: 16 q x 64 keys bf16 (+8 pad)
  const int tid = threadIdx.x;
  const int bh = blockIdx.x & 31, bb = bh >> 4, h = bh & 15;
  const int qt = 31 - (int)(blockIdx.x >> 5);   // heavy first
  const int w = tid >> 6, lane = tid & 63;
  const int l15 = lane & 15, quad = lane >> 4;
  const int sr = lane >> 3, cs = lane & 7;
  u16* Pme = Pw + w * (16*72);
  const int w16l = w*16 + l15;
  const int dquad = quad*4;

  const u16* qp = qkv + ((size_t)(bb*2048 + qt*64 + w16l))*3072 + h*64 + quad*8;
  const bf16x8 aq0 = *(const bf16x8*)qp;
  const bf16x8 aq1 = *(const bf16x8*)(qp + 32);

  f32x4 o[4];
  const f32x4 zero = {0.f,0.f,0.f,0.f};
  #pragma unroll
  for (int dt = 0; dt < 4; ++dt) o[dt] = zero;
  float l = 0.f;

  const u16* kbase = qkv + (size_t)bb*2048*3072 + 1024 + h*64;
  const u16* vbase = Vt + (size_t)bh*64*2048;

  for (int kt = 0; kt <= qt; ++kt) {
    __syncthreads();
    #pragma unroll
    for (int it = 0; it < 2; ++it) {
      int r = it*32 + w*8 + sr;
      int c = cs ^ (r & 7);
      glds16(kbase + (size_t)(kt*64 + r)*3072 + c*8, &Kl[(it*32 + w*8) * 64]);
      glds16(vbase + (size_t)r*2048 + kt*64 + c*8,   &Vl[(it*32 + w*8) * 64]);
    }
    __syncthreads();
    bf16x8 ak[4][2], av[4][2];
    #pragma unroll
    for (int nt = 0; nt < 4; ++nt) {
      int R = nt*16 + l15;
      #pragma unroll
      for (int kk = 0; kk < 2; ++kk) {
        ak[nt][kk] = *(const bf16x8*)&Kl[R*64 + ((kk*4 + quad) ^ (R & 7)) * 8];
        av[nt][kk] = *(const bf16x8*)&Vl[R*64 + ((kk*4 + quad) ^ (R & 7)) * 8];
      }
    }
    f32x4 sv[4];
    #pragma unroll
    for (int nt = 0; nt < 4; ++nt) {
      f32x4 s = zero;
      s = __builtin_amdgcn_mfma_f32_16x16x32_bf16(ak[nt][0], aq0, s, 0, 0, 0);
      s = __builtin_amdgcn_mfma_f32_16x16x32_bf16(ak[nt][1], aq1, s, 0, 0, 0);
      sv[nt] = s;
    }
    if (kt == qt) {                           // diagonal tile: causal mask
      #pragma unroll
      for (int nt = 0; nt < 4; ++nt)
        #pragma unroll
        for (int r = 0; r < 4; ++r)
          if (nt*16 + dquad + r > w16l) sv[nt][r] = -1e30f;
    }
    float pv[4][4];
    #pragma unroll
    for (int nt = 0; nt < 4; ++nt)
      #pragma unroll
      for (int r = 0; r < 4; ++r)
        pv[nt][r] = exp2f(sv[nt][r]);         // fixed max=0 (bounded scores)
    l += ((pv[0][0]+pv[0][1])+(pv[0][2]+pv[0][3]))
       + ((pv[1][0]+pv[1][1])+(pv[1][2]+pv[1][3]))
       + ((pv[2][0]+pv[2][1])+(pv[2][2]+pv[2][3]))
       + ((pv[3][0]+pv[3][1])+(pv[3][2]+pv[3][3]));
    #pragma unroll
    for (int nt = 0; nt < 4; ++nt) {
      uint2 pr;
      pr.x = pk_trunc(pv[nt][0], pv[nt][1]);
      pr.y = pk_trunc(pv[nt][2], pv[nt][3]);
      *(uint2*)&Pme[l15*72 + nt*16 + dquad] = pr;
    }
    const bf16x8 bp0 = *(const bf16x8*)&Pme[l15*72 + quad*8];
    const bf16x8 bp1 = *(const bf16x8*)&Pme[l15*72 + 32 + quad*8];
    #pragma unroll
    for (int dt = 0; dt < 4; ++dt) {
      o[dt] = __builtin_amdgcn_mfma_f32_16x16x32_bf16(av[dt][0], bp0, o[dt], 0, 0, 0);
      o[dt] = __builtin_amdgcn_mfma_f32_16x16x32_bf16(av[dt][1], bp1, o[dt], 0, 0, 0);
    }
  }
  float lt = l;
  lt += __shfl_xor(lt, 16);
  lt += __shfl_xor(lt, 32);
  float inv = 1.f / lt;
  u16* yp = y + ((size_t)(bb*2048 + qt*64 + w16l))*1024 + h*64;
  #pragma unroll
  for (int dt = 0; dt < 4; ++dt) {
    uint2 pk;
    pk.x = pack2(o[dt][0]*inv, o[dt][1]*inv);
    pk.y = pack2(o[dt][2]*inv, o[dt][3]*inv);
    *(uint2*)(yp + dt*16 + dquad) = pk;
  }
}

// ---------------------------------------------------------------------------
extern "C" void kernel_launch(void* const* d_in, const int* in_sizes, int n_in,
                              void* d_out, int out_size, void* d_ws, size_t ws_size,
                              hipStream_t stream) {
  const float* x      = (const float*)d_in[0];
  const float* ln1_g  = (const float*)d_in[1];
  const float* ln1_b  = (const float*)d_in[2];
  const float* w_attn = (const float*)d_in[3];
  const float* b_attn = (const float*)d_in[4];
  const float* w_proj = (const float*)d_in[5];
  const float* b_proj = (const float*)d_in[6];
  const float* ln2_g  = (const float*)d_in[7];
  const float* ln2_b  = (const float*)d_in[8];
  const float* w_fc   = (const float*)d_in[9];
  const float* b_fc   = (const float*)d_in[10];
  const float* w_fc2  = (const float*)d_in[11];
  const float* b_fc2  = (const float*)d_in[12];

  char* ws = (char*)d_ws;
  u16*   wt_attn = (u16*)(ws);                 // [3072,1024] bf16
  u16*   wt_proj = (u16*)(ws + 6291456);       // [1024,1024]
  u16*   wt_fc   = (u16*)(ws + 8388608);       // [4096,1024]
  u16*   wt_fc2  = (u16*)(ws + 16777216);      // [1024,4096]
  u16*   h1      = (u16*)(ws + 25165824);      // [4096,1024] bf16 (dead after qkv GEMM)
  u16*   qkvb    = (u16*)(ws + 33554432);      // [4096,3072] bf16
  u16*   yb      = (u16*)(ws + 58720256);      // [4096,1024] bf16
  float* x2      = (float*)(ws + 67108864);    // [4096,1024] f32
  u16*   h2  = h1;
  u16*   vtb = h1;                             // Vt [32,64,2048] bf16, aliases h1
  u16*   act = qkvb;                           // [4096,4096] bf16 (yb dead by then)
  u16*   pk2 = (u16*)(ws);                     // fc2 partials [2][4096,1024] bf16
                                               // (aliases wt_* head, dead after fc)

  // 4 weight transposes + LN1, one dispatch
  prep_k<<<dim3(16384), 256, 0, stream>>>(w_attn, w_proj, w_fc, w_fc2,
                                          wt_attn, wt_proj, wt_fc, wt_fc2,
                                          x, ln1_g, ln1_b, h1);
  gemm_k<4,4,3><<<dim3(32, 24), 256, 0, stream>>>(h1, wt_attn, b_attn, nullptr,
                                                  (void*)qkvb, 4096, 3072, 1024, 1024);
  vt_k<<<dim3(64, 64), 256, 0, stream>>>(qkvb, vtb);      // h1 dead now
  attn_k<<<dim3(1024), 256, 0, stream>>>(qkvb, vtb, yb);
  gemm_k<1,2,3><<<dim3(64, 8), 256, 0, stream>>>(yb, wt_proj, b_proj, x,
                                                 (void*)x2, 4096, 1024, 1024, 1024);
  ln_k<<<4096, 256, 0, stream>>>(x2, ln2_g, ln2_b, h2);   // Vt dead now
  gemm_k<2,4,3><<<dim3(32, 32), 256, 0, stream>>>(h2, wt_fc, b_fc, nullptr,
                                                  (void*)act, 4096, 4096, 1024, 1024);
  // fc2 split-K x2, single dispatch (1024 blocks = 4/CU), bf16 partials
  gemm_k<5,2,3><<<dim3(64, 16), 256, 0, stream>>>(act, wt_fc2, b_fc2, nullptr,
                                                  (void*)pk2, 4096, 1024, 2048, 4096);
  cmb_k<<<4096, 256, 0, stream>>>(pk2, b_fc2, x2, (float*)d_out);
}